// Round 4
// baseline (116.505 us; speedup 1.0000x reference)
//
#include <hip/hip_runtime.h>
#include <stdint.h>

#define BB 4
#define CC 256
#define NN 4096
#define II 32
#define NS (NN/128)  // 32 super-steps; each covers 128 m (32 per parity wave)

typedef __attribute__((ext_vector_type(8))) short short8;
typedef __attribute__((ext_vector_type(4))) short short4v;
typedef __attribute__((ext_vector_type(4))) float float4v;

union U8 { short8 s8; unsigned u[4]; };

#define MFMA16(a,b,c) __builtin_amdgcn_mfma_f32_16x16x32_bf16(a,b,c,0,0,0)
#define LOG2E 1.4426950408889634f

typedef const __attribute__((address_space(1))) unsigned int GU32;
typedef __attribute__((address_space(3))) unsigned int LU32;

__device__ inline unsigned short f2bf(float f){
  unsigned u = __float_as_uint(f);
  u += 0x7fffu + ((u >> 16) & 1u);
  return (unsigned short)(u >> 16);
}
__device__ inline unsigned pack2(float a, float b){
  return (unsigned)f2bf(a) | ((unsigned)f2bf(b) << 16);
}
__device__ inline short8 cvt8(float4v a, float4v b){
  U8 t;
  t.u[0] = pack2(a[0], a[1]); t.u[1] = pack2(a[2], a[3]);
  t.u[2] = pack2(b[0], b[1]); t.u[3] = pack2(b[2], b[3]);
  return t.s8;
}
__device__ inline unsigned cvtpk(float lo, float hi){
  unsigned r;
  asm("v_cvt_pk_bf16_f32 %0, %1, %2" : "=v"(r) : "v"(lo), "v"(hi));
  return r;
}

// ---------------- kernel 1: x[b][c][n] f32 -> xt[b][n][c] bf16 ----------------
__global__ __launch_bounds__(256) void kxt(const float* __restrict__ x,
                                           unsigned short* __restrict__ xt){
  __shared__ float t[32][33];
  const int b = blockIdx.z, cb = blockIdx.y * 32, nb = blockIdx.x * 32;
  const int tid = threadIdx.x;
  const int rr = tid >> 3, q4 = (tid & 7) * 4;
  float4v v = *(const float4v*)(x + ((size_t)(b*CC + cb + rr))*NN + nb + q4);
  t[rr][q4+0] = v[0]; t[rr][q4+1] = v[1]; t[rr][q4+2] = v[2]; t[rr][q4+3] = v[3];
  __syncthreads();
  short4v o;
  o[0] = (short)f2bf(t[q4+0][rr]);
  o[1] = (short)f2bf(t[q4+1][rr]);
  o[2] = (short)f2bf(t[q4+2][rr]);
  o[3] = (short)f2bf(t[q4+3][rr]);
  *(short4v*)(xt + ((size_t)(b*NN + nb + rr))*CC + cb + q4) = o;
}

// ---------------- kernel 2: q,k projection ----------------
__global__ __launch_bounds__(256) void kqk(const unsigned short* __restrict__ xt,
    const float* __restrict__ Wq, const float* __restrict__ bq,
    const float* __restrict__ Wk, const float* __restrict__ bk,
    unsigned short* __restrict__ qws, unsigned short* __restrict__ kws){
  const int tid = threadIdx.x, w = tid >> 6, lane = tid & 63;
  const int r = lane & 15, g = lane >> 4;
  const int gw = blockIdx.x * 4 + w;
  const int b = gw >> 8, nt = gw & 255, n0 = nt * 16;
  const unsigned short* abase = xt + ((size_t)(b*NN + n0 + r))*CC + g*8;
  float4v acc[4];
  float4v z4 = {0.f,0.f,0.f,0.f};
  #pragma unroll
  for (int ni = 0; ni < 4; ++ni) acc[ni] = z4;
  #pragma unroll
  for (int kk = 0; kk < 8; ++kk){
    short8 a = *(const short8*)(abase + kk*32);
    #pragma unroll
    for (int ni = 0; ni < 4; ++ni){
      const float* Wp = (ni < 2 ? Wq : Wk) + (size_t)((ni&1)*16 + r)*CC + kk*32 + g*8;
      short8 bf = cvt8(*(const float4v*)Wp, *(const float4v*)(Wp + 4));
      acc[ni] = MFMA16(a, bf, acc[ni]);
    }
  }
  #pragma unroll
  for (int ni = 0; ni < 4; ++ni){
    const float bias = (ni < 2 ? bq : bk)[(ni&1)*16 + r];
    const float scale = (ni < 2) ? LOG2E : 1.0f;
    unsigned short* dst = (ni < 2 ? qws : kws);
    #pragma unroll
    for (int rr = 0; rr < 4; ++rr){
      int n = n0 + g*4 + rr;
      dst[((size_t)b*NN + n)*II + (ni&1)*16 + r] = f2bf((acc[ni][rr] + bias) * scale);
    }
  }
}

// ---------------- kernel 3: v projection ----------------
__global__ __launch_bounds__(256) void kvp(const unsigned short* __restrict__ xt,
    const float* __restrict__ Wv, const float* __restrict__ bv,
    unsigned short* __restrict__ vws){
  const int tid = threadIdx.x, w = tid >> 6, lane = tid & 63;
  const int r = lane & 15, g = lane >> 4;
  const int gw = blockIdx.x * 4 + w;
  const int b = gw >> 10, rest = gw & 1023;
  const int c0 = (rest >> 6) * 16, n0 = (rest & 63) * 64;
  float4v acc[4];
  float4v z4 = {0.f,0.f,0.f,0.f};
  #pragma unroll
  for (int ni = 0; ni < 4; ++ni) acc[ni] = z4;
  #pragma unroll
  for (int kk = 0; kk < 8; ++kk){
    const float* Wp = Wv + ((size_t)(c0 + r))*CC + kk*32 + g*8;
    short8 a = cvt8(*(const float4v*)Wp, *(const float4v*)(Wp + 4));
    #pragma unroll
    for (int ni = 0; ni < 4; ++ni){
      short8 bf = *(const short8*)(xt + ((size_t)(b*NN + n0 + ni*16 + r))*CC + kk*32 + g*8);
      acc[ni] = MFMA16(a, bf, acc[ni]);
    }
  }
  #pragma unroll
  for (int ni = 0; ni < 4; ++ni){
    #pragma unroll
    for (int rr = 0; rr < 4; ++rr){
      int c = c0 + g*4 + rr;
      vws[((size_t)b*CC + c)*NN + n0 + ni*16 + r] = f2bf(acc[ni][rr] + bv[c]);
    }
  }
}

// ---------------- kernel 4: fused flash attention + epilogue ----------------
// block: c-tile 128 (blockIdx.y) x n-tile 64 (blockIdx.x), batch z; 8 waves.
// wave w: nsub = w&1 -> n-cols [nsub*32, +32); p = w>>1 in [0,4) -> 32-m chunk
// within a 128-m super-step. V staged via global_load_lds (linear LDS dest,
// inverse-swizzled global source; reads apply the swizzle).
union SMem {
  unsigned short v[2][4][128*32];   // 64KB: [dbuf][m-chunk][c-row][m-seg]
  float comb[3][2][64][36];         // 55KB: parity-combine scratch
};

__global__ __launch_bounds__(512, 4) void kattn(
    const unsigned short* __restrict__ qws, const unsigned short* __restrict__ kws,
    const unsigned short* __restrict__ vws, const float* __restrict__ x,
    const float* __restrict__ gamma, float* __restrict__ out){
  __shared__ __align__(16) SMem sm;
  const int tid = threadIdx.x, w = tid >> 6, lane = tid & 63;
  const int r = lane & 15, g = lane >> 4;
  const int nsub = w & 1, p = w >> 1;
  const int b = blockIdx.z, c0 = blockIdx.y * 128, n0 = blockIdx.x * 64;
  const int nw0 = n0 + nsub * 32;

  // hoisted Q B-frags (loop-invariant), pre-scaled by log2e
  short8 qf0 = *(const short8*)(qws + ((size_t)(b*NN + nw0 +      r))*II + g*8);
  short8 qf1 = *(const short8*)(qws + ((size_t)(b*NN + nw0 + 16 + r))*II + g*8);

  // permuted k-row index: A-frag row r holds K[8*(r>>2)+(r&3)] (+4 for tile 1)
  const int M0 = ((r >> 2) << 3) + (r & 3);
  const unsigned short* kptr = kws + ((size_t)b*NN + p*32 + M0)*II + g*8;

  float4v z4 = {0.f,0.f,0.f,0.f};
  float4v acc[8][2];
  #pragma unroll
  for (int mi = 0; mi < 8; ++mi){ acc[mi][0] = z4; acc[mi][1] = z4; }
  float sacc0 = 0.f, sacc1 = 0.f;

  // ---- V staging via global_load_lds: 32 instrs x 1KB cover [4 chunks][128c][32m]
  // LDS dest linear: instr iw -> bytes [iw*1024, +1024), lane l -> +l*16.
  // Content swizzle: lds[chunk][row][s'] = V[row][chunk*32 + (s' ^ ((row>>1)&3))*8 ..+8]
  const unsigned short* vsrc = vws + ((size_t)b*CC + c0)*NN;
  const int iw0 = w * 4;
  #define MKSP(i) (vsrc + (size_t)(((((iw0+(i))&7)<<4) + (lane>>2)))*NN \
                   + (((iw0+(i))>>3)*32) + (((lane&3)^((lane>>3)&3))*8))
  const unsigned short* sp0 = MKSP(0);
  const unsigned short* sp1 = MKSP(1);
  const unsigned short* sp2 = MKSP(2);
  const unsigned short* sp3 = MKSP(3);
  const int d0 = (iw0+0)*512, d1 = (iw0+1)*512, d2 = (iw0+2)*512, d3 = (iw0+3)*512;
  #define STAGE4(lb, mofs) do{ \
    __builtin_amdgcn_global_load_lds((GU32*)(sp0+(mofs)), (LU32*)((lb)+d0), 16, 0, 0); \
    __builtin_amdgcn_global_load_lds((GU32*)(sp1+(mofs)), (LU32*)((lb)+d1), 16, 0, 0); \
    __builtin_amdgcn_global_load_lds((GU32*)(sp2+(mofs)), (LU32*)((lb)+d2), 16, 0, 0); \
    __builtin_amdgcn_global_load_lds((GU32*)(sp3+(mofs)), (LU32*)((lb)+d3), 16, 0, 0); \
  }while(0)

  // V read base within chunk: swizzled segment, mi-independent
  const int vbase = (r*4 + (g ^ ((r >> 1) & 3))) * 8;

  STAGE4(&sm.v[0][0][0], 0);   // prologue: stage super-step 0

  for (int s = 0; s < NS; ++s){
    __syncthreads();                       // drains vmcnt -> sm.v[s&1] ready; prior reads done
    if (s + 1 < NS) STAGE4(&sm.v[(s+1)&1][0][0], (s+1)*128);
    // K A-frags for this wave's 32-m chunk (L2-resident)
    const unsigned short* kp = kptr + (size_t)s*4096;
    short8 kf0 = *(const short8*)(kp);
    short8 kf1 = *(const short8*)(kp + 4*II);
    // V A-frags from LDS (this wave's chunk p)
    const unsigned short* vb = &sm.v[s & 1][p][0] + vbase;
    short8 va[8];
    #pragma unroll
    for (int mi = 0; mi < 8; ++mi) va[mi] = *(const short8*)(vb + mi*512);
    // S^T = mfma(K, Q): lane holds S[m][n] * log2e
    float4v s00 = MFMA16(kf0, qf0, z4);
    float4v s01 = MFMA16(kf0, qf1, z4);
    float4v s10 = MFMA16(kf1, qf0, z4);
    float4v s11 = MFMA16(kf1, qf1, z4);
    // exp2 + per-lane partial row sums + in-lane bf16 pack
    float e0 = __builtin_exp2f(s00[0]), e1 = __builtin_exp2f(s00[1]);
    float e2 = __builtin_exp2f(s00[2]), e3 = __builtin_exp2f(s00[3]);
    float e4 = __builtin_exp2f(s10[0]), e5 = __builtin_exp2f(s10[1]);
    float e6 = __builtin_exp2f(s10[2]), e7 = __builtin_exp2f(s10[3]);
    sacc0 += (e0 + e1 + e2 + e3) + (e4 + e5 + e6 + e7);
    U8 bf0;
    bf0.u[0] = cvtpk(e0, e1); bf0.u[1] = cvtpk(e2, e3);
    bf0.u[2] = cvtpk(e4, e5); bf0.u[3] = cvtpk(e6, e7);
    float f0 = __builtin_exp2f(s01[0]), f1 = __builtin_exp2f(s01[1]);
    float f2 = __builtin_exp2f(s01[2]), f3 = __builtin_exp2f(s01[3]);
    float f4 = __builtin_exp2f(s11[0]), f5 = __builtin_exp2f(s11[1]);
    float f6 = __builtin_exp2f(s11[2]), f7 = __builtin_exp2f(s11[3]);
    sacc1 += (f0 + f1 + f2 + f3) + (f4 + f5 + f6 + f7);
    U8 bf1;
    bf1.u[0] = cvtpk(f0, f1); bf1.u[1] = cvtpk(f2, f3);
    bf1.u[2] = cvtpk(f4, f5); bf1.u[3] = cvtpk(f6, f7);
    // PV: each va feeds 2 MFMAs (the LDS-traffic halving)
    #pragma unroll
    for (int mi = 0; mi < 8; ++mi){
      acc[mi][0] = MFMA16(va[mi], bf0.s8, acc[mi][0]);
      acc[mi][1] = MFMA16(va[mi], bf1.s8, acc[mi][1]);
    }
  }

  // ---- combine 4 parity waves via LDS (2 rounds), epilogue by p==0 waves
  __syncthreads();
  if (p){
    float* cw = &sm.comb[p-1][nsub][lane][0];
    #pragma unroll
    for (int mi = 0; mi < 4; ++mi)
      #pragma unroll
      for (int ni = 0; ni < 2; ++ni)
        #pragma unroll
        for (int rr = 0; rr < 4; ++rr) cw[mi*8 + ni*4 + rr] = acc[mi][ni][rr];
    cw[32] = sacc0; cw[33] = sacc1;
  }
  __syncthreads();
  if (!p){
    #pragma unroll
    for (int pp = 0; pp < 3; ++pp){
      const float* cr = &sm.comb[pp][nsub][lane][0];
      #pragma unroll
      for (int mi = 0; mi < 4; ++mi)
        #pragma unroll
        for (int ni = 0; ni < 2; ++ni)
          #pragma unroll
          for (int rr = 0; rr < 4; ++rr) acc[mi][ni][rr] += cr[mi*8 + ni*4 + rr];
      sacc0 += cr[32]; sacc1 += cr[33];
    }
  }
  __syncthreads();
  if (p){
    float* cw = &sm.comb[p-1][nsub][lane][0];
    #pragma unroll
    for (int mi = 0; mi < 4; ++mi)
      #pragma unroll
      for (int ni = 0; ni < 2; ++ni)
        #pragma unroll
        for (int rr = 0; rr < 4; ++rr) cw[mi*8 + ni*4 + rr] = acc[mi+4][ni][rr];
  }
  __syncthreads();
  if (!p){
    #pragma unroll
    for (int pp = 0; pp < 3; ++pp){
      const float* cr = &sm.comb[pp][nsub][lane][0];
      #pragma unroll
      for (int mi = 0; mi < 4; ++mi)
        #pragma unroll
        for (int ni = 0; ni < 2; ++ni)
          #pragma unroll
          for (int rr = 0; rr < 4; ++rr) acc[mi+4][ni][rr] += cr[mi*8 + ni*4 + rr];
    }
    // full row sums: reduce over the 4 g-lanes sharing r
    sacc0 += __shfl_xor(sacc0, 16); sacc0 += __shfl_xor(sacc0, 32);
    sacc1 += __shfl_xor(sacc1, 16); sacc1 += __shfl_xor(sacc1, 32);
    const float inv0 = 1.0f / sacc0, inv1 = 1.0f / sacc1;
    const float gmv = gamma[0];
    #pragma unroll
    for (int mi = 0; mi < 8; ++mi){
      const int c = c0 + mi*16 + g*4;
      #pragma unroll
      for (int ni = 0; ni < 2; ++ni){
        const float inv = ni ? inv1 : inv0;
        const size_t base = ((size_t)b*CC + c)*NN + nw0 + ni*16 + r;
        float4v a = acc[mi][ni];
        #pragma unroll
        for (int rr = 0; rr < 4; ++rr){
          const size_t idx = base + (size_t)rr*NN;
          out[idx] = gmv * (a[rr] * inv) + x[idx];
        }
      }
    }
  }
}

extern "C" void kernel_launch(void* const* d_in, const int* in_sizes, int n_in,
                              void* d_out, int out_size, void* d_ws, size_t ws_size,
                              hipStream_t stream){
  const float* x  = (const float*)d_in[0];
  const float* Wq = (const float*)d_in[1];
  const float* bq = (const float*)d_in[2];
  const float* Wk = (const float*)d_in[3];
  const float* bk = (const float*)d_in[4];
  const float* Wv = (const float*)d_in[5];
  const float* bv = (const float*)d_in[6];
  const float* gm = (const float*)d_in[7];
  float* out = (float*)d_out;

  unsigned short* xt  = (unsigned short*)d_ws;              // [B][N][C]  8 MB
  unsigned short* qws = xt  + (size_t)BB*NN*CC;             // [B][N][32] 1 MB
  unsigned short* kws = qws + (size_t)BB*NN*II;             // [B][N][32] 1 MB
  unsigned short* vws = kws + (size_t)BB*NN*II;             // [B][C][N]  8 MB

  kxt<<<dim3(NN/32, CC/32, BB), 256, 0, stream>>>(x, xt);
  kqk<<<dim3(BB*NN/16/4), 256, 0, stream>>>(xt, Wq, bq, Wk, bk, qws, kws);
  kvp<<<dim3(BB*(CC/16)*(NN/64)/4), 256, 0, stream>>>(xt, Wv, bv, vws);
  kattn<<<dim3(NN/64, 2, BB), 512, 0, stream>>>(qws, kws, vws, x, gm, out);
}